// Round 15
// baseline (217.512 us; speedup 1.0000x reference)
//
#include <hip/hip_runtime.h>
#include <hip/hip_bf16.h>

#define N_NODES 20000
#define MPAD    20096
#define E_EDGES 400000
#define LATENT 128
#define H1 256
#define HIDDEN 512
#define OUT_D 64
#define HEADS 4
#define NEG_SLOPE 0.2f
#define NBLK_SCAN ((N_NODES + 255) / 256)   // 79

typedef __attribute__((ext_vector_type(8))) __bf16 bf16x8;
typedef __attribute__((ext_vector_type(4))) float f32x4;
typedef __attribute__((ext_vector_type(4))) unsigned short u16x4;

__device__ __forceinline__ unsigned short f2bf(float f) {
    union { float f; unsigned int u; } v; v.f = f;
    unsigned int r = v.u + 0x7fffu + ((v.u >> 16) & 1u);  // RNE
    return (unsigned short)(r >> 16);
}
__device__ __forceinline__ float bf2f(unsigned short u) {
    union { unsigned int u; float f; } v; v.u = ((unsigned int)u) << 16;
    return v.f;
}

// ---------------- weights transpose-convert + degree histogram (ONE launch) ----------------
#define SEG1 (LATENT * H1)
#define SEG2 (H1 * HIDDEN)
#define SEG3 (HIDDEN * HEADS * OUT_D)
#define WTOT (SEG1 + SEG2 + SEG3)
__global__ __launch_bounds__(256)
void prep_kernel(const float* __restrict__ W1, const float* __restrict__ W2,
                 const float* __restrict__ Wg, const int* __restrict__ ei,
                 unsigned short* __restrict__ W1t, unsigned short* __restrict__ W2t,
                 unsigned short* __restrict__ Wgt, int* __restrict__ deg) {
    int t = blockIdx.x * blockDim.x + threadIdx.x;
    if (t < SEG1) { int k = t >> 8, n = t & 255; W1t[n * LATENT + k] = f2bf(W1[t]); return; }
    t -= SEG1;
    if (t < SEG2) { int k = t >> 9, n = t & 511; W2t[n * H1 + k] = f2bf(W2[t]); return; }
    t -= SEG2;
    if (t < SEG3) { int k = t >> 8, n = t & 255; Wgt[n * HIDDEN + k] = f2bf(Wg[t]); return; }
    t -= SEG3;
    if (t < E_EDGES) atomicAdd(&deg[ei[E_EDGES + t]], 1);
}

// ---------------- fully fused MLP + att coefs ----------------
// TM=32, 628 blocks, 256 threads. KEY CHANGE vs R12: launch_bounds(256,4) caps VGPR at
// 128, and layer 2 runs as two sequential 64-col halves so the peak live set
// (acc 32 + weight dbuf 32 + af 8 + addr ~20 ≈ 90) FITS — in R8-R12 layer-2's
// acc(64)+dbuf(64) > 88 forced the compiler to sink the prefetch, leaving a serial
// per-MFMA load chain (~5100 cyc/kt, the measured 60 us plateau).
#define TM 32
#define ZPITCH 136
#define XPITCH 264
#define X2PITCH 520
__global__ __launch_bounds__(256, 4)
void mlp_all_kernel(const float* __restrict__ z,
                    const unsigned short* __restrict__ W1t,
                    const unsigned short* __restrict__ W2t,
                    const unsigned short* __restrict__ Wgt,
                    const float* __restrict__ b1, const float* __restrict__ b2,
                    const float* __restrict__ att_src, const float* __restrict__ att_dst,
                    unsigned short* __restrict__ hb,
                    float* __restrict__ a_src, float* __restrict__ a_dst) {
    __shared__ unsigned short x2s[TM * X2PITCH];   // 33.3 KB; first 8.7 KB aliased as zbf
    __shared__ unsigned short x1s[TM * XPITCH];    // 16.9 KB (50.2 KB total)
    unsigned short* zbf = x2s;
    const int tid = threadIdx.x;
    const int wave = tid >> 6, lane = tid & 63;
    const int m0 = blockIdx.x * TM;
    const int fr = lane & 15, q = lane >> 4;

#define LDW1(kt, t)      (*(const bf16x8*)(W1t + (size_t)(nb1 + (t) * 16 + fr) * LATENT + (kt) * 32 + q * 8))
#define LDW2H(nh, kt, t) (*(const bf16x8*)(W2t + (size_t)(nb2 + (nh) * 64 + (t) * 16 + fr) * H1 + (kt) * 32 + q * 8))
#define LDW3(kt, t)      (*(const bf16x8*)(Wgt + (size_t)(nb3 + (t) * 16 + fr) * HIDDEN + (kt) * 32 + q * 8))

    const int nb1 = wave * 64;
    const int nb2 = wave * 128;
    const int head = wave;
    const int nb3 = wave * 64;

    bf16x8 w1a[4], w1b[4];
#pragma unroll
    for (int t = 0; t < 4; t++) w1a[t] = LDW1(0, t);

    {
        const int r = tid >> 3, c0 = (tid & 7) * 16;
        const int zrow = min(m0 + r, N_NODES - 1);
        const float* zp = z + (size_t)zrow * LATENT + c0;
#pragma unroll
        for (int i = 0; i < 4; i++) {
            f32x4 v = *(const f32x4*)(zp + i * 4);
            u16x4 p = { f2bf(v[0]), f2bf(v[1]), f2bf(v[2]), f2bf(v[3]) };
            *(u16x4*)(zbf + r * ZPITCH + c0 + i * 4) = p;
        }
    }
    __syncthreads();

    // ---- layer 1: K=128 (4 kt) ----
    f32x4 acc1[2][4] = {};
#pragma unroll
    for (int kt = 0; kt < 4; kt++) {
        bf16x8* wc = (kt & 1) ? w1b : w1a;
        bf16x8* wn = (kt & 1) ? w1a : w1b;
        if (kt < 3) {
#pragma unroll
            for (int t = 0; t < 4; t++) wn[t] = LDW1(kt + 1, t);
        }
        bf16x8 af[2];
#pragma unroll
        for (int t = 0; t < 2; t++)
            af[t] = *(const bf16x8*)(zbf + (t * 16 + fr) * ZPITCH + kt * 32 + q * 8);
#pragma unroll
        for (int mt = 0; mt < 2; mt++)
#pragma unroll
            for (int nt = 0; nt < 4; nt++)
                acc1[mt][nt] = __builtin_amdgcn_mfma_f32_16x16x32_bf16(
                    wc[nt], af[mt], acc1[mt][nt], 0, 0, 0);
    }

    // prefetch layer-2 half-0 kt=0 (hides latency across the epilogue + barrier)
    bf16x8 w2a[4], w2b[4];
#pragma unroll
    for (int t = 0; t < 4; t++) w2a[t] = LDW2H(0, 0, t);

    // layer-1 epilogue -> x1s
#pragma unroll
    for (int nt = 0; nt < 4; nt++) {
        const int n = nb1 + nt * 16 + q * 4;
        const f32x4 bv = *(const f32x4*)(b1 + n);
#pragma unroll
        for (int mt = 0; mt < 2; mt++) {
            u16x4 p;
#pragma unroll
            for (int r = 0; r < 4; r++) p[r] = f2bf(fmaxf(acc1[mt][nt][r] + bv[r], 0.f));
            *(u16x4*)(x1s + (mt * 16 + fr) * XPITCH + n) = p;
        }
    }
    __syncthreads();

    // ---- layer 2: K=256 (8 kt), two sequential 64-col halves (dbuf fits the 128 cap) ----
#pragma unroll
    for (int nh = 0; nh < 2; nh++) {
        if (nh == 1) {
#pragma unroll
            for (int t = 0; t < 4; t++) w2a[t] = LDW2H(1, 0, t);   // one bubble per half
        }
        f32x4 acc2[2][4] = {};
#pragma unroll
        for (int kt = 0; kt < 8; kt++) {
            bf16x8* wc = (kt & 1) ? w2b : w2a;
            bf16x8* wn = (kt & 1) ? w2a : w2b;
            if (kt < 7) {
#pragma unroll
                for (int t = 0; t < 4; t++) wn[t] = LDW2H(nh, kt + 1, t);
            }
            bf16x8 af[2];
#pragma unroll
            for (int t = 0; t < 2; t++)
                af[t] = *(const bf16x8*)(x1s + (t * 16 + fr) * XPITCH + kt * 32 + q * 8);
#pragma unroll
            for (int mt = 0; mt < 2; mt++)
#pragma unroll
                for (int nt = 0; nt < 4; nt++)
                    acc2[mt][nt] = __builtin_amdgcn_mfma_f32_16x16x32_bf16(
                        wc[nt], af[mt], acc2[mt][nt], 0, 0, 0);
        }
        // epilogue -> x2s cols nb2 + nh*64 (zbf alias dead since layer 1)
#pragma unroll
        for (int nt = 0; nt < 4; nt++) {
            const int n = nb2 + nh * 64 + nt * 16 + q * 4;
            const f32x4 bv = *(const f32x4*)(b2 + n);
#pragma unroll
            for (int mt = 0; mt < 2; mt++) {
                u16x4 p;
#pragma unroll
                for (int r = 0; r < 4; r++) p[r] = f2bf(fmaxf(acc2[mt][nt][r] + bv[r], 0.f));
                *(u16x4*)(x2s + (mt * 16 + fr) * X2PITCH + n) = p;
            }
        }
    }

    bf16x8 w3a[4], w3b[4];
#pragma unroll
    for (int t = 0; t < 4; t++) w3a[t] = LDW3(0, t);
    __syncthreads();

    // ---- layer 3: K=512 (16 kt) + att epilogue ----
    f32x4 acc3[2][4] = {};
#pragma unroll
    for (int kt = 0; kt < 16; kt++) {
        bf16x8* wc = (kt & 1) ? w3b : w3a;
        bf16x8* wn = (kt & 1) ? w3a : w3b;
        if (kt < 15) {
#pragma unroll
            for (int t = 0; t < 4; t++) wn[t] = LDW3(kt + 1, t);
        }
        bf16x8 af[2];
#pragma unroll
        for (int t = 0; t < 2; t++)
            af[t] = *(const bf16x8*)(x2s + (t * 16 + fr) * X2PITCH + kt * 32 + q * 8);
#pragma unroll
        for (int mt = 0; mt < 2; mt++)
#pragma unroll
            for (int nt = 0; nt < 4; nt++)
                acc3[mt][nt] = __builtin_amdgcn_mfma_f32_16x16x32_bf16(
                    wc[nt], af[mt], acc3[mt][nt], 0, 0, 0);
    }

    {
        f32x4 asv[4], adv[4];
#pragma unroll
        for (int nt = 0; nt < 4; nt++) {
            asv[nt] = *(const f32x4*)(att_src + head * OUT_D + nt * 16 + q * 4);
            adv[nt] = *(const f32x4*)(att_dst + head * OUT_D + nt * 16 + q * 4);
        }
#pragma unroll
        for (int mt = 0; mt < 2; mt++) {
            const int row = m0 + mt * 16 + fr;
            float vs = 0.f, vd = 0.f;
#pragma unroll
            for (int nt = 0; nt < 4; nt++) {
                u16x4 p;
#pragma unroll
                for (int r = 0; r < 4; r++) {
                    float x = acc3[mt][nt][r];
                    p[r] = f2bf(x);
                    vs += x * asv[nt][r];
                    vd += x * adv[nt][r];
                }
                *(u16x4*)(hb + (size_t)row * (HEADS * OUT_D) + head * OUT_D + nt * 16 + q * 4) = p;
            }
            vs += __shfl_xor(vs, 16, 64); vs += __shfl_xor(vs, 32, 64);
            vd += __shfl_xor(vd, 16, 64); vd += __shfl_xor(vd, 32, 64);
            if (q == 0 && row < N_NODES) {
                a_src[row * HEADS + head] = vs;
                a_dst[row * HEADS + head] = vd;
            }
        }
    }
#undef LDW1
#undef LDW2H
#undef LDW3
}

// ---------------- CSR build ----------------
__global__ __launch_bounds__(256) void scan_a(const int* __restrict__ deg,
                                              int* __restrict__ t, int* __restrict__ bsum) {
    int i = blockIdx.x * 256 + threadIdx.x;
    int lane = threadIdx.x & 63, wave = threadIdx.x >> 6;
    int v = (i < N_NODES) ? deg[i] + 1 : 0;
    int s = v;
#pragma unroll
    for (int off = 1; off < 64; off <<= 1) {
        int u = __shfl_up(s, off, 64);
        if (lane >= off) s += u;
    }
    __shared__ int wsum[4];
    if (lane == 63) wsum[wave] = s;
    __syncthreads();
    int woff = 0;
    for (int w = 0; w < wave; w++) woff += wsum[w];
    s += woff;
    if (i < N_NODES) t[i] = s;
    if (threadIdx.x == 255) bsum[blockIdx.x] = s;
}

__global__ __launch_bounds__(256) void scan_c(const int* __restrict__ t, const int* __restrict__ deg,
                                              const int* __restrict__ bsum,
                                              int* __restrict__ row_start, int* __restrict__ cursor) {
    __shared__ int boff_s;
    if (threadIdx.x < 64) {
        int s = 0;
        for (int i = threadIdx.x; i < blockIdx.x; i += 64) s += bsum[i];
#pragma unroll
        for (int off = 32; off > 0; off >>= 1) s += __shfl_xor(s, off, 64);
        if (threadIdx.x == 0) boff_s = s;
    }
    __syncthreads();
    int i = blockIdx.x * 256 + threadIdx.x;
    if (i >= N_NODES) return;
    int incl = t[i] + boff_s;
    int start = incl - (deg[i] + 1);
    row_start[i] = start;
    cursor[i] = start;
}

// ---------------- scatter edges + store exp(leaky(logit)) per head ----------------
__global__ void scatter_logits(const int* __restrict__ ei, int* __restrict__ cursor,
                               const int* __restrict__ row_start, const int* __restrict__ deg,
                               const float* __restrict__ a_src, const float* __restrict__ a_dst,
                               int* __restrict__ adj, float* __restrict__ eex) {
    int t = blockIdx.x * blockDim.x + threadIdx.x;
    if (t >= E_EDGES + N_NODES) return;
    int s, d, slot;
    if (t < E_EDGES) {
        s = ei[t]; d = ei[E_EDGES + t];
        slot = atomicAdd(&cursor[d], 1);
    } else {
        s = d = t - E_EDGES;
        slot = row_start[d] + deg[d];
    }
    adj[slot] = s;
    f32x4 as = *(const f32x4*)(a_src + s * HEADS);
    f32x4 ad = *(const f32x4*)(a_dst + d * HEADS);
    f32x4 o;
#pragma unroll
    for (int h = 0; h < HEADS; h++) {
        float v = as[h] + ad[h];
        v = (v > 0.f) ? v : NEG_SLOPE * v;
        o[h] = __expf(fminf(v, 60.f));
    }
    *(f32x4*)(eex + (size_t)slot * HEADS) = o;
}

// ---------------- fused segment-softmax + gather-aggregate: one wave per node ----------------
__global__ __launch_bounds__(256) void fused_gat(const int* __restrict__ adj,
                                                 const int* __restrict__ row_start,
                                                 const int* __restrict__ deg,
                                                 const float* __restrict__ eex,
                                                 const unsigned short* __restrict__ hb,
                                                 const float* __restrict__ bias_g,
                                                 float* __restrict__ out) {
    const int wave = threadIdx.x >> 6, lane = threadIdx.x & 63;
    const int d = blockIdx.x * 4 + wave;      // N_NODES % 4 == 0
    const int base = row_start[d];
    const int cnt = deg[d] + 1;
    const int h = lane >> 4, j = lane & 15;

    __shared__ float lw[4][HEADS][32];
    __shared__ int   si[4][32];

    // single pass: stash ex + sum
    float sm = 0.f;
    for (int e = j; e < cnt; e += 16) {
        float ex = eex[(size_t)(base + e) * HEADS + h];
        if (e < 32) {
            lw[wave][h][e] = ex;
            if (h == 0) si[wave][e] = adj[base + e];
        }
        sm += ex;
    }
#pragma unroll
    for (int off = 1; off < 16; off <<= 1) sm += __shfl_xor(sm, off, 64);
    const float inv = 1.f / (sm + 1e-16f);

    // phase 2: weighted gather, 16 loads in flight, then 8/4/scalar tails
    float a0 = 0.f, a1 = 0.f, a2 = 0.f, a3 = 0.f;
    const int lim = cnt < 32 ? cnt : 32;
    const unsigned short* hp = hb + h * OUT_D + j * 4;
    int e = 0;
    for (; e + 15 < lim; e += 16) {
        int   sx[16]; float wx[16]; u16x4 gx[16];
#pragma unroll
        for (int u = 0; u < 16; u++) { sx[u] = si[wave][e + u]; wx[u] = lw[wave][h][e + u]; }
#pragma unroll
        for (int u = 0; u < 16; u++) gx[u] = *(const u16x4*)(hp + (size_t)sx[u] * (HEADS * OUT_D));
#pragma unroll
        for (int u = 0; u < 16; u++) {
            a0 += wx[u] * bf2f(gx[u][0]); a1 += wx[u] * bf2f(gx[u][1]);
            a2 += wx[u] * bf2f(gx[u][2]); a3 += wx[u] * bf2f(gx[u][3]);
        }
    }
    for (; e + 7 < lim; e += 8) {
        int   sx[8]; float wx[8]; u16x4 gx[8];
#pragma unroll
        for (int u = 0; u < 8; u++) { sx[u] = si[wave][e + u]; wx[u] = lw[wave][h][e + u]; }
#pragma unroll
        for (int u = 0; u < 8; u++) gx[u] = *(const u16x4*)(hp + (size_t)sx[u] * (HEADS * OUT_D));
#pragma unroll
        for (int u = 0; u < 8; u++) {
            a0 += wx[u] * bf2f(gx[u][0]); a1 += wx[u] * bf2f(gx[u][1]);
            a2 += wx[u] * bf2f(gx[u][2]); a3 += wx[u] * bf2f(gx[u][3]);
        }
    }
    for (; e + 3 < lim; e += 4) {
        int   sx[4]; float wx[4]; u16x4 gx[4];
#pragma unroll
        for (int u = 0; u < 4; u++) { sx[u] = si[wave][e + u]; wx[u] = lw[wave][h][e + u]; }
#pragma unroll
        for (int u = 0; u < 4; u++) gx[u] = *(const u16x4*)(hp + (size_t)sx[u] * (HEADS * OUT_D));
#pragma unroll
        for (int u = 0; u < 4; u++) {
            a0 += wx[u] * bf2f(gx[u][0]); a1 += wx[u] * bf2f(gx[u][1]);
            a2 += wx[u] * bf2f(gx[u][2]); a3 += wx[u] * bf2f(gx[u][3]);
        }
    }
    for (; e < lim; e++) {
        int s = si[wave][e];
        float w = lw[wave][h][e];
        u16x4 g = *(const u16x4*)(hp + (size_t)s * (HEADS * OUT_D));
        a0 += w * bf2f(g[0]); a1 += w * bf2f(g[1]);
        a2 += w * bf2f(g[2]); a3 += w * bf2f(g[3]);
    }
    for (int e2 = 32; e2 < cnt; e2++) {   // rare (deg >= 32)
        int s = adj[base + e2];
        float w = eex[(size_t)(base + e2) * HEADS + h];
        u16x4 g = *(const u16x4*)(hp + (size_t)s * (HEADS * OUT_D));
        a0 += w * bf2f(g[0]); a1 += w * bf2f(g[1]);
        a2 += w * bf2f(g[2]); a3 += w * bf2f(g[3]);
    }
    a0 *= inv; a1 *= inv; a2 *= inv; a3 *= inv;

    a0 += __shfl_xor(a0, 16, 64); a0 += __shfl_xor(a0, 32, 64);
    a1 += __shfl_xor(a1, 16, 64); a1 += __shfl_xor(a1, 32, 64);
    a2 += __shfl_xor(a2, 16, 64); a2 += __shfl_xor(a2, 32, 64);
    a3 += __shfl_xor(a3, 16, 64); a3 += __shfl_xor(a3, 32, 64);
    if (lane < 16) {
        f32x4 bg = *(const f32x4*)(bias_g + lane * 4);
        f32x4 r = { 0.25f * a0 + bg[0], 0.25f * a1 + bg[1],
                    0.25f * a2 + bg[2], 0.25f * a3 + bg[3] };
        *(f32x4*)(out + (size_t)d * OUT_D + lane * 4) = r;
    }
}

extern "C" void kernel_launch(void* const* d_in, const int* in_sizes, int n_in,
                              void* d_out, int out_size, void* d_ws, size_t ws_size,
                              hipStream_t stream) {
    const float* z       = (const float*)d_in[0];
    const float* W1      = (const float*)d_in[1];
    const float* b1      = (const float*)d_in[2];
    const float* W2      = (const float*)d_in[3];
    const float* b2      = (const float*)d_in[4];
    const float* Wg      = (const float*)d_in[5];
    const float* att_src = (const float*)d_in[6];
    const float* att_dst = (const float*)d_in[7];
    const float* bias_g  = (const float*)d_in[8];
    const int*   ei      = (const int*)d_in[9];
    float* out = (float*)d_out;

    char* ws = (char*)d_ws;
    size_t off = 0;
    auto carve = [&](size_t bytes) { void* p = ws + off; off += (bytes + 255) & ~(size_t)255; return p; };

    unsigned short* W1t = (unsigned short*)carve((size_t)H1 * LATENT * 2);
    unsigned short* W2t = (unsigned short*)carve((size_t)HIDDEN * H1 * 2);
    unsigned short* Wgt = (unsigned short*)carve((size_t)(HEADS * OUT_D) * HIDDEN * 2);
    unsigned short* hb  = (unsigned short*)carve((size_t)MPAD * HEADS * OUT_D * 2);
    float* a_src = (float*)carve((size_t)N_NODES * HEADS * 4);
    float* a_dst = (float*)carve((size_t)N_NODES * HEADS * 4);
    int* deg       = (int*)carve((size_t)N_NODES * 4);
    int* tmp_scan  = (int*)carve((size_t)N_NODES * 4);
    int* bsum      = (int*)carve((size_t)NBLK_SCAN * 4);
    int* row_start = (int*)carve((size_t)N_NODES * 4);
    int* cursor    = (int*)carve((size_t)N_NODES * 4);
    int* adj       = (int*)carve((size_t)(E_EDGES + N_NODES) * 4);
    float* eex     = (float*)carve((size_t)(E_EDGES + N_NODES) * HEADS * 4);

    hipMemsetAsync(deg, 0, (size_t)N_NODES * 4, stream);

    prep_kernel<<<(WTOT + E_EDGES + 255) / 256, 256, 0, stream>>>(
        W1, W2, Wg, ei, W1t, W2t, Wgt, deg);

    scan_a<<<NBLK_SCAN, 256, 0, stream>>>(deg, tmp_scan, bsum);
    scan_c<<<NBLK_SCAN, 256, 0, stream>>>(tmp_scan, deg, bsum, row_start, cursor);

    // fused MLP: layer-2 column halves + 128-VGPR cap so the weight dbuf finally fits
    mlp_all_kernel<<<MPAD / TM, 256, 0, stream>>>(
        z, W1t, W2t, Wgt, b1, b2, att_src, att_dst, hb, a_src, a_dst);

    scatter_logits<<<(E_EDGES + N_NODES + 255) / 256, 256, 0, stream>>>(
        ei, cursor, row_start, deg, a_src, a_dst, adj, eex);

    fused_gat<<<N_NODES / 4, 256, 0, stream>>>(adj, row_start, deg, eex, hb, bias_g, out);
}

// Round 16
// 210.311 us; speedup vs baseline: 1.0342x; 1.0342x over previous
//
#include <hip/hip_runtime.h>
#include <hip/hip_bf16.h>

#define N_NODES 20000
#define MPAD    20096
#define E_EDGES 400000
#define LATENT 128
#define H1 256
#define HIDDEN 512
#define OUT_D 64
#define HEADS 4
#define NEG_SLOPE 0.2f
#define NBLK_SCAN ((N_NODES + 255) / 256)   // 79

typedef __attribute__((ext_vector_type(8))) __bf16 bf16x8;
typedef __attribute__((ext_vector_type(4))) float f32x4;
typedef __attribute__((ext_vector_type(4))) unsigned short u16x4;

__device__ __forceinline__ unsigned short f2bf(float f) {
    union { float f; unsigned int u; } v; v.f = f;
    unsigned int r = v.u + 0x7fffu + ((v.u >> 16) & 1u);  // RNE
    return (unsigned short)(r >> 16);
}
__device__ __forceinline__ float bf2f(unsigned short u) {
    union { unsigned int u; float f; } v; v.u = ((unsigned int)u) << 16;
    return v.f;
}

// ---------------- weights transpose-convert + degree histogram (ONE launch) ----------------
#define SEG1 (LATENT * H1)
#define SEG2 (H1 * HIDDEN)
#define SEG3 (HIDDEN * HEADS * OUT_D)
#define WTOT (SEG1 + SEG2 + SEG3)
__global__ __launch_bounds__(256)
void prep_kernel(const float* __restrict__ W1, const float* __restrict__ W2,
                 const float* __restrict__ Wg, const int* __restrict__ ei,
                 unsigned short* __restrict__ W1t, unsigned short* __restrict__ W2t,
                 unsigned short* __restrict__ Wgt, int* __restrict__ deg) {
    int t = blockIdx.x * blockDim.x + threadIdx.x;
    if (t < SEG1) { int k = t >> 8, n = t & 255; W1t[n * LATENT + k] = f2bf(W1[t]); return; }
    t -= SEG1;
    if (t < SEG2) { int k = t >> 9, n = t & 511; W2t[n * H1 + k] = f2bf(W2[t]); return; }
    t -= SEG2;
    if (t < SEG3) { int k = t >> 8, n = t & 255; Wgt[n * HIDDEN + k] = f2bf(Wg[t]); return; }
    t -= SEG3;
    if (t < E_EDGES) atomicAdd(&deg[ei[E_EDGES + t]], 1);
}

// ---------------- fully fused MLP + att coefs (R15 config — 58.6 us, best measured) ----------------
// TM=32, 628 blocks, 256 threads; layer 2 as two sequential 64-col halves; VGPR 68.
// NOTE (R8-R15): the HIP compiler sinks ALL register prefetches regardless of budget
// (policy, not pressure — proven by R15's 68-VGPR build still sinking). ~59 us is the
// practical floor for this MLP shape: per-layer K too small for pipeline ramp.
#define TM 32
#define ZPITCH 136
#define XPITCH 264
#define X2PITCH 520
__global__ __launch_bounds__(256, 4)
void mlp_all_kernel(const float* __restrict__ z,
                    const unsigned short* __restrict__ W1t,
                    const unsigned short* __restrict__ W2t,
                    const unsigned short* __restrict__ Wgt,
                    const float* __restrict__ b1, const float* __restrict__ b2,
                    const float* __restrict__ att_src, const float* __restrict__ att_dst,
                    unsigned short* __restrict__ hb,
                    float* __restrict__ a_src, float* __restrict__ a_dst) {
    __shared__ unsigned short x2s[TM * X2PITCH];   // 33.3 KB; first 8.7 KB aliased as zbf
    __shared__ unsigned short x1s[TM * XPITCH];    // 16.9 KB (50.2 KB total)
    unsigned short* zbf = x2s;
    const int tid = threadIdx.x;
    const int wave = tid >> 6, lane = tid & 63;
    const int m0 = blockIdx.x * TM;
    const int fr = lane & 15, q = lane >> 4;

#define LDW1(kt, t)      (*(const bf16x8*)(W1t + (size_t)(nb1 + (t) * 16 + fr) * LATENT + (kt) * 32 + q * 8))
#define LDW2H(nh, kt, t) (*(const bf16x8*)(W2t + (size_t)(nb2 + (nh) * 64 + (t) * 16 + fr) * H1 + (kt) * 32 + q * 8))
#define LDW3(kt, t)      (*(const bf16x8*)(Wgt + (size_t)(nb3 + (t) * 16 + fr) * HIDDEN + (kt) * 32 + q * 8))

    const int nb1 = wave * 64;
    const int nb2 = wave * 128;
    const int head = wave;
    const int nb3 = wave * 64;

    bf16x8 w1a[4], w1b[4];
#pragma unroll
    for (int t = 0; t < 4; t++) w1a[t] = LDW1(0, t);

    {
        const int r = tid >> 3, c0 = (tid & 7) * 16;
        const int zrow = min(m0 + r, N_NODES - 1);
        const float* zp = z + (size_t)zrow * LATENT + c0;
#pragma unroll
        for (int i = 0; i < 4; i++) {
            f32x4 v = *(const f32x4*)(zp + i * 4);
            u16x4 p = { f2bf(v[0]), f2bf(v[1]), f2bf(v[2]), f2bf(v[3]) };
            *(u16x4*)(zbf + r * ZPITCH + c0 + i * 4) = p;
        }
    }
    __syncthreads();

    // ---- layer 1: K=128 (4 kt) ----
    f32x4 acc1[2][4] = {};
#pragma unroll
    for (int kt = 0; kt < 4; kt++) {
        bf16x8* wc = (kt & 1) ? w1b : w1a;
        bf16x8* wn = (kt & 1) ? w1a : w1b;
        if (kt < 3) {
#pragma unroll
            for (int t = 0; t < 4; t++) wn[t] = LDW1(kt + 1, t);
        }
        bf16x8 af[2];
#pragma unroll
        for (int t = 0; t < 2; t++)
            af[t] = *(const bf16x8*)(zbf + (t * 16 + fr) * ZPITCH + kt * 32 + q * 8);
#pragma unroll
        for (int mt = 0; mt < 2; mt++)
#pragma unroll
            for (int nt = 0; nt < 4; nt++)
                acc1[mt][nt] = __builtin_amdgcn_mfma_f32_16x16x32_bf16(
                    wc[nt], af[mt], acc1[mt][nt], 0, 0, 0);
    }

    bf16x8 w2a[4], w2b[4];
#pragma unroll
    for (int t = 0; t < 4; t++) w2a[t] = LDW2H(0, 0, t);

    // layer-1 epilogue -> x1s
#pragma unroll
    for (int nt = 0; nt < 4; nt++) {
        const int n = nb1 + nt * 16 + q * 4;
        const f32x4 bv = *(const f32x4*)(b1 + n);
#pragma unroll
        for (int mt = 0; mt < 2; mt++) {
            u16x4 p;
#pragma unroll
            for (int r = 0; r < 4; r++) p[r] = f2bf(fmaxf(acc1[mt][nt][r] + bv[r], 0.f));
            *(u16x4*)(x1s + (mt * 16 + fr) * XPITCH + n) = p;
        }
    }
    __syncthreads();

    // ---- layer 2: K=256 (8 kt), two sequential 64-col halves ----
#pragma unroll
    for (int nh = 0; nh < 2; nh++) {
        if (nh == 1) {
#pragma unroll
            for (int t = 0; t < 4; t++) w2a[t] = LDW2H(1, 0, t);
        }
        f32x4 acc2[2][4] = {};
#pragma unroll
        for (int kt = 0; kt < 8; kt++) {
            bf16x8* wc = (kt & 1) ? w2b : w2a;
            bf16x8* wn = (kt & 1) ? w2a : w2b;
            if (kt < 7) {
#pragma unroll
                for (int t = 0; t < 4; t++) wn[t] = LDW2H(nh, kt + 1, t);
            }
            bf16x8 af[2];
#pragma unroll
            for (int t = 0; t < 2; t++)
                af[t] = *(const bf16x8*)(x1s + (t * 16 + fr) * XPITCH + kt * 32 + q * 8);
#pragma unroll
            for (int mt = 0; mt < 2; mt++)
#pragma unroll
                for (int nt = 0; nt < 4; nt++)
                    acc2[mt][nt] = __builtin_amdgcn_mfma_f32_16x16x32_bf16(
                        wc[nt], af[mt], acc2[mt][nt], 0, 0, 0);
        }
#pragma unroll
        for (int nt = 0; nt < 4; nt++) {
            const int n = nb2 + nh * 64 + nt * 16 + q * 4;
            const f32x4 bv = *(const f32x4*)(b2 + n);
#pragma unroll
            for (int mt = 0; mt < 2; mt++) {
                u16x4 p;
#pragma unroll
                for (int r = 0; r < 4; r++) p[r] = f2bf(fmaxf(acc2[mt][nt][r] + bv[r], 0.f));
                *(u16x4*)(x2s + (mt * 16 + fr) * X2PITCH + n) = p;
            }
        }
    }

    bf16x8 w3a[4], w3b[4];
#pragma unroll
    for (int t = 0; t < 4; t++) w3a[t] = LDW3(0, t);
    __syncthreads();

    // ---- layer 3: K=512 (16 kt) + att epilogue ----
    f32x4 acc3[2][4] = {};
#pragma unroll
    for (int kt = 0; kt < 16; kt++) {
        bf16x8* wc = (kt & 1) ? w3b : w3a;
        bf16x8* wn = (kt & 1) ? w3a : w3b;
        if (kt < 15) {
#pragma unroll
            for (int t = 0; t < 4; t++) wn[t] = LDW3(kt + 1, t);
        }
        bf16x8 af[2];
#pragma unroll
        for (int t = 0; t < 2; t++)
            af[t] = *(const bf16x8*)(x2s + (t * 16 + fr) * X2PITCH + kt * 32 + q * 8);
#pragma unroll
        for (int mt = 0; mt < 2; mt++)
#pragma unroll
            for (int nt = 0; nt < 4; nt++)
                acc3[mt][nt] = __builtin_amdgcn_mfma_f32_16x16x32_bf16(
                    wc[nt], af[mt], acc3[mt][nt], 0, 0, 0);
    }

    {
        f32x4 asv[4], adv[4];
#pragma unroll
        for (int nt = 0; nt < 4; nt++) {
            asv[nt] = *(const f32x4*)(att_src + head * OUT_D + nt * 16 + q * 4);
            adv[nt] = *(const f32x4*)(att_dst + head * OUT_D + nt * 16 + q * 4);
        }
#pragma unroll
        for (int mt = 0; mt < 2; mt++) {
            const int row = m0 + mt * 16 + fr;
            float vs = 0.f, vd = 0.f;
#pragma unroll
            for (int nt = 0; nt < 4; nt++) {
                u16x4 p;
#pragma unroll
                for (int r = 0; r < 4; r++) {
                    float x = acc3[mt][nt][r];
                    p[r] = f2bf(x);
                    vs += x * asv[nt][r];
                    vd += x * adv[nt][r];
                }
                *(u16x4*)(hb + (size_t)row * (HEADS * OUT_D) + head * OUT_D + nt * 16 + q * 4) = p;
            }
            vs += __shfl_xor(vs, 16, 64); vs += __shfl_xor(vs, 32, 64);
            vd += __shfl_xor(vd, 16, 64); vd += __shfl_xor(vd, 32, 64);
            if (q == 0 && row < N_NODES) {
                a_src[row * HEADS + head] = vs;
                a_dst[row * HEADS + head] = vd;
            }
        }
    }
#undef LDW1
#undef LDW2H
#undef LDW3
}

// ---------------- CSR build ----------------
__global__ __launch_bounds__(256) void scan_a(const int* __restrict__ deg,
                                              int* __restrict__ t, int* __restrict__ bsum) {
    int i = blockIdx.x * 256 + threadIdx.x;
    int lane = threadIdx.x & 63, wave = threadIdx.x >> 6;
    int v = (i < N_NODES) ? deg[i] + 1 : 0;
    int s = v;
#pragma unroll
    for (int off = 1; off < 64; off <<= 1) {
        int u = __shfl_up(s, off, 64);
        if (lane >= off) s += u;
    }
    __shared__ int wsum[4];
    if (lane == 63) wsum[wave] = s;
    __syncthreads();
    int woff = 0;
    for (int w = 0; w < wave; w++) woff += wsum[w];
    s += woff;
    if (i < N_NODES) t[i] = s;
    if (threadIdx.x == 255) bsum[blockIdx.x] = s;
}

__global__ __launch_bounds__(256) void scan_c(const int* __restrict__ t, const int* __restrict__ deg,
                                              const int* __restrict__ bsum,
                                              int* __restrict__ row_start, int* __restrict__ cursor) {
    __shared__ int boff_s;
    if (threadIdx.x < 64) {
        int s = 0;
        for (int i = threadIdx.x; i < blockIdx.x; i += 64) s += bsum[i];
#pragma unroll
        for (int off = 32; off > 0; off >>= 1) s += __shfl_xor(s, off, 64);
        if (threadIdx.x == 0) boff_s = s;
    }
    __syncthreads();
    int i = blockIdx.x * 256 + threadIdx.x;
    if (i >= N_NODES) return;
    int incl = t[i] + boff_s;
    int start = incl - (deg[i] + 1);
    row_start[i] = start;
    cursor[i] = start;
}

// ---------------- scatter edges + store exp(leaky(logit)) per head ----------------
__global__ void scatter_logits(const int* __restrict__ ei, int* __restrict__ cursor,
                               const int* __restrict__ row_start, const int* __restrict__ deg,
                               const float* __restrict__ a_src, const float* __restrict__ a_dst,
                               int* __restrict__ adj, float* __restrict__ eex) {
    int t = blockIdx.x * blockDim.x + threadIdx.x;
    if (t >= E_EDGES + N_NODES) return;
    int s, d, slot;
    if (t < E_EDGES) {
        s = ei[t]; d = ei[E_EDGES + t];
        slot = atomicAdd(&cursor[d], 1);
    } else {
        s = d = t - E_EDGES;
        slot = row_start[d] + deg[d];
    }
    adj[slot] = s;
    f32x4 as = *(const f32x4*)(a_src + s * HEADS);
    f32x4 ad = *(const f32x4*)(a_dst + d * HEADS);
    f32x4 o;
#pragma unroll
    for (int h = 0; h < HEADS; h++) {
        float v = as[h] + ad[h];
        v = (v > 0.f) ? v : NEG_SLOPE * v;
        o[h] = __expf(fminf(v, 60.f));
    }
    *(f32x4*)(eex + (size_t)slot * HEADS) = o;
}

// ---------------- fused segment-softmax + gather-aggregate (R14 version — champion) ----------------
__global__ __launch_bounds__(256) void fused_gat(const int* __restrict__ adj,
                                                 const int* __restrict__ row_start,
                                                 const int* __restrict__ deg,
                                                 const float* __restrict__ eex,
                                                 const unsigned short* __restrict__ hb,
                                                 const float* __restrict__ bias_g,
                                                 float* __restrict__ out) {
    const int wave = threadIdx.x >> 6, lane = threadIdx.x & 63;
    const int d = blockIdx.x * 4 + wave;      // N_NODES % 4 == 0
    const int base = row_start[d];
    const int cnt = deg[d] + 1;
    const int h = lane >> 4, j = lane & 15;

    __shared__ float lw[4][HEADS][32];
    __shared__ int   si[4][32];

    // single pass: stash ex + sum
    float sm = 0.f;
    for (int e = j; e < cnt; e += 16) {
        float ex = eex[(size_t)(base + e) * HEADS + h];
        if (e < 32) {
            lw[wave][h][e] = ex;
            if (h == 0) si[wave][e] = adj[base + e];
        }
        sm += ex;
    }
#pragma unroll
    for (int off = 1; off < 16; off <<= 1) sm += __shfl_xor(sm, off, 64);
    const float inv = 1.f / (sm + 1e-16f);

    // phase 2: weighted gather, 8 loads in flight; inv folded at the end
    float a0 = 0.f, a1 = 0.f, a2 = 0.f, a3 = 0.f;
    const int lim = cnt < 32 ? cnt : 32;
    const unsigned short* hp = hb + h * OUT_D + j * 4;
    int e = 0;
    for (; e + 7 < lim; e += 8) {
        int   sx[8]; float wx[8]; u16x4 gx[8];
#pragma unroll
        for (int u = 0; u < 8; u++) { sx[u] = si[wave][e + u]; wx[u] = lw[wave][h][e + u]; }
#pragma unroll
        for (int u = 0; u < 8; u++) gx[u] = *(const u16x4*)(hp + (size_t)sx[u] * (HEADS * OUT_D));
#pragma unroll
        for (int u = 0; u < 8; u++) {
            a0 += wx[u] * bf2f(gx[u][0]); a1 += wx[u] * bf2f(gx[u][1]);
            a2 += wx[u] * bf2f(gx[u][2]); a3 += wx[u] * bf2f(gx[u][3]);
        }
    }
    for (; e + 3 < lim; e += 4) {
        int   sx[4]; float wx[4]; u16x4 gx[4];
#pragma unroll
        for (int u = 0; u < 4; u++) { sx[u] = si[wave][e + u]; wx[u] = lw[wave][h][e + u]; }
#pragma unroll
        for (int u = 0; u < 4; u++) gx[u] = *(const u16x4*)(hp + (size_t)sx[u] * (HEADS * OUT_D));
#pragma unroll
        for (int u = 0; u < 4; u++) {
            a0 += wx[u] * bf2f(gx[u][0]); a1 += wx[u] * bf2f(gx[u][1]);
            a2 += wx[u] * bf2f(gx[u][2]); a3 += wx[u] * bf2f(gx[u][3]);
        }
    }
    for (; e < lim; e++) {
        int s = si[wave][e];
        float w = lw[wave][h][e];
        u16x4 g = *(const u16x4*)(hp + (size_t)s * (HEADS * OUT_D));
        a0 += w * bf2f(g[0]); a1 += w * bf2f(g[1]);
        a2 += w * bf2f(g[2]); a3 += w * bf2f(g[3]);
    }
    for (int e2 = 32; e2 < cnt; e2++) {   // rare (deg >= 32)
        int s = adj[base + e2];
        float w = eex[(size_t)(base + e2) * HEADS + h];
        u16x4 g = *(const u16x4*)(hp + (size_t)s * (HEADS * OUT_D));
        a0 += w * bf2f(g[0]); a1 += w * bf2f(g[1]);
        a2 += w * bf2f(g[2]); a3 += w * bf2f(g[3]);
    }
    a0 *= inv; a1 *= inv; a2 *= inv; a3 *= inv;

    a0 += __shfl_xor(a0, 16, 64); a0 += __shfl_xor(a0, 32, 64);
    a1 += __shfl_xor(a1, 16, 64); a1 += __shfl_xor(a1, 32, 64);
    a2 += __shfl_xor(a2, 16, 64); a2 += __shfl_xor(a2, 32, 64);
    a3 += __shfl_xor(a3, 16, 64); a3 += __shfl_xor(a3, 32, 64);
    if (lane < 16) {
        f32x4 bg = *(const f32x4*)(bias_g + lane * 4);
        f32x4 r = { 0.25f * a0 + bg[0], 0.25f * a1 + bg[1],
                    0.25f * a2 + bg[2], 0.25f * a3 + bg[3] };
        *(f32x4*)(out + (size_t)d * OUT_D + lane * 4) = r;
    }
}

extern "C" void kernel_launch(void* const* d_in, const int* in_sizes, int n_in,
                              void* d_out, int out_size, void* d_ws, size_t ws_size,
                              hipStream_t stream) {
    const float* z       = (const float*)d_in[0];
    const float* W1      = (const float*)d_in[1];
    const float* b1      = (const float*)d_in[2];
    const float* W2      = (const float*)d_in[3];
    const float* b2      = (const float*)d_in[4];
    const float* Wg      = (const float*)d_in[5];
    const float* att_src = (const float*)d_in[6];
    const float* att_dst = (const float*)d_in[7];
    const float* bias_g  = (const float*)d_in[8];
    const int*   ei      = (const int*)d_in[9];
    float* out = (float*)d_out;

    char* ws = (char*)d_ws;
    size_t off = 0;
    auto carve = [&](size_t bytes) { void* p = ws + off; off += (bytes + 255) & ~(size_t)255; return p; };

    unsigned short* W1t = (unsigned short*)carve((size_t)H1 * LATENT * 2);
    unsigned short* W2t = (unsigned short*)carve((size_t)HIDDEN * H1 * 2);
    unsigned short* Wgt = (unsigned short*)carve((size_t)(HEADS * OUT_D) * HIDDEN * 2);
    unsigned short* hb  = (unsigned short*)carve((size_t)MPAD * HEADS * OUT_D * 2);
    float* a_src = (float*)carve((size_t)N_NODES * HEADS * 4);
    float* a_dst = (float*)carve((size_t)N_NODES * HEADS * 4);
    int* deg       = (int*)carve((size_t)N_NODES * 4);
    int* tmp_scan  = (int*)carve((size_t)N_NODES * 4);
    int* bsum      = (int*)carve((size_t)NBLK_SCAN * 4);
    int* row_start = (int*)carve((size_t)N_NODES * 4);
    int* cursor    = (int*)carve((size_t)N_NODES * 4);
    int* adj       = (int*)carve((size_t)(E_EDGES + N_NODES) * 4);
    float* eex     = (float*)carve((size_t)(E_EDGES + N_NODES) * HEADS * 4);

    hipMemsetAsync(deg, 0, (size_t)N_NODES * 4, stream);

    prep_kernel<<<(WTOT + E_EDGES + 255) / 256, 256, 0, stream>>>(
        W1, W2, Wg, ei, W1t, W2t, Wgt, deg);

    scan_a<<<NBLK_SCAN, 256, 0, stream>>>(deg, tmp_scan, bsum);
    scan_c<<<NBLK_SCAN, 256, 0, stream>>>(tmp_scan, deg, bsum, row_start, cursor);

    mlp_all_kernel<<<MPAD / TM, 256, 0, stream>>>(
        z, W1t, W2t, Wgt, b1, b2, att_src, att_dst, hb, a_src, a_dst);

    scatter_logits<<<(E_EDGES + N_NODES + 255) / 256, 256, 0, stream>>>(
        ei, cursor, row_start, deg, a_src, a_dst, adj, eex);

    fused_gat<<<N_NODES / 4, 256, 0, stream>>>(adj, row_start, deg, eex, hb, bias_g, out);
}